// Round 3
// baseline (103.831 us; speedup 1.0000x reference)
//
#include <hip/hip_runtime.h>

#define NF 13776
#define KMAX 8
#define EPS 1e-8f

// ---------------------------------------------------------------------------
// Per-face precompute: triangle coords (AoS) + AABB (SoA) + faces (SoA).
// Thread 0 also zero-inits the output (harness poisons d_out to 0xAA).
__global__ __launch_bounds__(256) void prep_kernel(
    const float* __restrict__ verts,   // [NV,3]
    const int*   __restrict__ faces,   // [NF*3]
    float* __restrict__ tri,           // [NF,9]
    float* __restrict__ lox, float* __restrict__ loy, float* __restrict__ loz,
    float* __restrict__ hix, float* __restrict__ hiy, float* __restrict__ hiz,
    int* __restrict__ f0, int* __restrict__ f1, int* __restrict__ f2,
    float* __restrict__ out)
{
    int f = blockIdx.x * blockDim.x + threadIdx.x;
    if (f == 0) out[0] = 0.0f;
    if (f >= NF) return;
    int ia = faces[3 * f + 0], ib = faces[3 * f + 1], ic = faces[3 * f + 2];
    f0[f] = ia; f1[f] = ib; f2[f] = ic;
    float ax = verts[3 * ia + 0], ay = verts[3 * ia + 1], az = verts[3 * ia + 2];
    float bx = verts[3 * ib + 0], by = verts[3 * ib + 1], bz = verts[3 * ib + 2];
    float cx = verts[3 * ic + 0], cy = verts[3 * ic + 1], cz = verts[3 * ic + 2];
    float* t = tri + 9 * f;
    t[0] = ax; t[1] = ay; t[2] = az;
    t[3] = bx; t[4] = by; t[5] = bz;
    t[6] = cx; t[7] = cy; t[8] = cz;
    lox[f] = fminf(ax, fminf(bx, cx));
    loy[f] = fminf(ay, fminf(by, cy));
    loz[f] = fminf(az, fminf(bz, cz));
    hix[f] = fmaxf(ax, fmaxf(bx, cx));
    hiy[f] = fmaxf(ay, fmaxf(by, cy));
    hiz[f] = fmaxf(az, fmaxf(bz, cz));
}

// ---------------------------------------------------------------------------
// Per-vertex term of the conical penalty: field of triangle s[9] evaluated at
// one query point (px,py,pz). SIGMA=0.5, POINT2PLANE=False, PENALIZE_OUTSIDE.
__device__ __forceinline__ float cone_pen_v(const float* s,
                                            float px, float py, float pz) {
    float e0x = s[3] - s[0], e0y = s[4] - s[1], e0z = s[5] - s[2];
    float e1x = s[6] - s[0], e1y = s[7] - s[1], e1z = s[8] - s[2];
    float nx = e0y * e1z - e0z * e1y;
    float ny = e0z * e1x - e0x * e1z;
    float nz = e0x * e1y - e0y * e1x;
    float inv = 1.0f / (sqrtf(nx * nx + ny * ny + nz * nz) + EPS);
    nx *= inv; ny *= inv; nz *= inv;
    const float third = 1.0f / 3.0f;
    float cx = (s[0] + s[3] + s[6]) * third;
    float cy = (s[1] + s[4] + s[7]) * third;
    float cz = (s[2] + s[5] + s[8]) * third;
    float ux = px - cx, uy = py - cy, uz = pz - cz;
    float h = ux * nx + uy * ny + uz * nz;
    float rx = ux - h * nx, ry = uy - h * ny, rz = uz - h * nz;
    float r = sqrtf(rx * rx + ry * ry + rz * rz);
    float radial = fmaxf(0.0f, 1.0f - 2.0f * r);        // 1 - r/SIGMA
    // relu(-h) + relu(h)*exp(-h/SIGMA) == h<0 ? -h : h*exp(-2h)
    float depth = (h < 0.0f) ? -h : h * expf(-2.0f * h);
    float phi = radial * depth;
    return phi * phi;                                    // POINT2PLANE=False
}

// ---------------------------------------------------------------------------
// One wave per receiver. 64 lanes test 64 candidates per chunk; ballot bits in
// lane order = ascending j, so taking the first (8-nc) set bits reproduces
// stable top_k exactly. Penalty spread over 48 lanes: pair k (8) x direction
// (2) x vertex (3).
__global__ __launch_bounds__(256) void coll_kernel(
    const float* __restrict__ tri,
    const float* __restrict__ lox, const float* __restrict__ loy,
    const float* __restrict__ loz, const float* __restrict__ hix,
    const float* __restrict__ hiy, const float* __restrict__ hiz,
    const int* __restrict__ f0, const int* __restrict__ f1,
    const int* __restrict__ f2,
    float* __restrict__ out)
{
    const int lane = threadIdx.x & 63;
    const int wid  = threadIdx.x >> 6;                   // wave in block
    const int i    = (blockIdx.x * blockDim.x + threadIdx.x) >> 6;  // receiver

    float psum = 0.0f;

    if (i < NF) {
        // receiver bbox + vertex ids (wave-uniform -> scalar broadcast)
        float blo0 = lox[i], blo1 = loy[i], blo2 = loz[i];
        float bhi0 = hix[i], bhi1 = hiy[i], bhi2 = hiz[i];
        int fa0 = f0[i], fa1 = f1[i], fa2 = f2[i];

        int nc = 0;
        int hj = -1;                                     // this lane's hit slot
        for (int base = 0; base < NF && nc < KMAX; base += 64) {
            int j = base + lane;
            bool valid = false;
            if (j < NF) {
                bool ov = (blo0 <= hix[j]) & (lox[j] <= bhi0)
                        & (blo1 <= hiy[j]) & (loy[j] <= bhi1)
                        & (blo2 <= hiz[j]) & (loz[j] <= bhi2);
                if (ov) {
                    int fb0 = f0[j], fb1 = f1[j], fb2 = f2[j];
                    bool share = (fb0 == fa0) | (fb0 == fa1) | (fb0 == fa2)
                               | (fb1 == fa0) | (fb1 == fa1) | (fb1 == fa2)
                               | (fb2 == fa0) | (fb2 == fa1) | (fb2 == fa2);
                    valid = !share;
                }
            }
            unsigned long long mask = __ballot(valid);
            int cnt  = __popcll(mask);
            int take = min(cnt, KMAX - nc);
            if (lane >= nc && lane < nc + take) {
                int t = lane - nc;                       // t-th set bit
                unsigned long long m = mask;
                for (int q = 0; q < t; ++q) m &= (m - 1);
                hj = base + __builtin_ctzll(m);
            }
            nc += take;
        }

        // Penalty: lane = k*6 + d*3 + v for k<8, d<2, v<3 -> lanes 0..47.
        int k = lane / 6;
        int r = lane - 6 * k;
        int d = r / 3;                                   // 0: recv field at intr verts
        int v = r - 3 * d;                               // vertex index
        int hjk = __shfl(hj, k & 7);
        if (lane < 48 && k < nc) {
            float st[9];
            const float* sp = tri + 9 * ((d == 0) ? i : hjk);   // field source
            const float* pp = tri + 9 * ((d == 0) ? hjk : i);   // query verts
#pragma unroll
            for (int q = 0; q < 9; ++q) st[q] = sp[q];
            psum = cone_pen_v(st, pp[3 * v + 0], pp[3 * v + 1], pp[3 * v + 2]);
        }
    }

    // 64-lane butterfly reduce, then block reduce, one atomic per block.
#pragma unroll
    for (int off = 32; off > 0; off >>= 1) psum += __shfl_xor(psum, off);
    __shared__ float wsum[4];
    if (lane == 0) wsum[wid] = psum;
    __syncthreads();
    if (threadIdx.x == 0)
        atomicAdd(out, wsum[0] + wsum[1] + wsum[2] + wsum[3]);
}

// ---------------------------------------------------------------------------
extern "C" void kernel_launch(void* const* d_in, const int* in_sizes, int n_in,
                              void* d_out, int out_size, void* d_ws, size_t ws_size,
                              hipStream_t stream) {
    const float* verts = (const float*)d_in[0];   // [1,NV,3] fp32
    const int*   faces = (const int*)d_in[1];     // [NF*3] int32
    float* out = (float*)d_out;                   // scalar fp32

    float* tri = (float*)d_ws;                    // NF*9
    float* lox = tri + NF * 9;
    float* loy = lox + NF;
    float* loz = loy + NF;
    float* hix = loz + NF;
    float* hiy = hix + NF;
    float* hiz = hiy + NF;
    int*   f0  = (int*)(hiz + NF);
    int*   f1  = f0 + NF;
    int*   f2  = f1 + NF;                         // total NF*18*4 B ~ 992 KB

    prep_kernel<<<(NF + 255) / 256, 256, 0, stream>>>(
        verts, faces, tri, lox, loy, loz, hix, hiy, hiz, f0, f1, f2, out);
    // one wave (64 lanes) per receiver face
    coll_kernel<<<(NF * 64 + 255) / 256, 256, 0, stream>>>(
        tri, lox, loy, loz, hix, hiy, hiz, f0, f1, f2, out);
}

// Round 4
// 66.743 us; speedup vs baseline: 1.5557x; 1.5557x over previous
//
#include <hip/hip_runtime.h>

#define NF   13776
#define NFP  13824            // padded to multiple of 64
#define KMAX 8
#define EPS  1e-8f
#define CBLK 2048             // coll blocks x 4 waves = 8192 waves (8/SIMD)

// ---------------------------------------------------------------------------
// Per-face precompute. Packed layout:
//   lo4[f] = {lox, loy, loz, asfloat(f0)}
//   hi4[f] = {hix, hiy, hiz, asfloat(f1)}
//   f2[f]  = third vertex id
//   tri[3f..3f+2] = 12 floats: ax ay az bx | by bz cx cy | cz 0 0 0
// Entries [NF, NFP) are +/-INF sentinels that can never overlap anything.
__global__ __launch_bounds__(256) void prep_kernel(
    const float* __restrict__ verts,   // [NV,3]
    const int*   __restrict__ faces,   // [NF*3]
    float4* __restrict__ tri,          // [NFP*3]
    float4* __restrict__ lo4, float4* __restrict__ hi4,
    int* __restrict__ f2)
{
    int f = blockIdx.x * blockDim.x + threadIdx.x;
    if (f >= NFP) return;
    if (f >= NF) {
        lo4[f] = make_float4(INFINITY, INFINITY, INFINITY, __int_as_float(-1));
        hi4[f] = make_float4(-INFINITY, -INFINITY, -INFINITY, __int_as_float(-1));
        f2[f]  = -1;
        return;
    }
    int ia = faces[3 * f + 0], ib = faces[3 * f + 1], ic = faces[3 * f + 2];
    float ax = verts[3 * ia + 0], ay = verts[3 * ia + 1], az = verts[3 * ia + 2];
    float bx = verts[3 * ib + 0], by = verts[3 * ib + 1], bz = verts[3 * ib + 2];
    float cx = verts[3 * ic + 0], cy = verts[3 * ic + 1], cz = verts[3 * ic + 2];
    tri[3 * f + 0] = make_float4(ax, ay, az, bx);
    tri[3 * f + 1] = make_float4(by, bz, cx, cy);
    tri[3 * f + 2] = make_float4(cz, 0.f, 0.f, 0.f);
    lo4[f] = make_float4(fminf(ax, fminf(bx, cx)),
                         fminf(ay, fminf(by, cy)),
                         fminf(az, fminf(bz, cz)), __int_as_float(ia));
    hi4[f] = make_float4(fmaxf(ax, fmaxf(bx, cx)),
                         fmaxf(ay, fmaxf(by, cy)),
                         fmaxf(az, fmaxf(bz, cz)), __int_as_float(ib));
    f2[f] = ic;
}

// ---------------------------------------------------------------------------
// Per-vertex conical penalty term: field of triangle s[9] at point (px,py,pz).
// SIGMA=0.5, POINT2PLANE=False, PENALIZE_OUTSIDE=True.
__device__ __forceinline__ float cone_pen_v(const float* s,
                                            float px, float py, float pz) {
    float e0x = s[3] - s[0], e0y = s[4] - s[1], e0z = s[5] - s[2];
    float e1x = s[6] - s[0], e1y = s[7] - s[1], e1z = s[8] - s[2];
    float nx = e0y * e1z - e0z * e1y;
    float ny = e0z * e1x - e0x * e1z;
    float nz = e0x * e1y - e0y * e1x;
    float inv = 1.0f / (sqrtf(nx * nx + ny * ny + nz * nz) + EPS);
    nx *= inv; ny *= inv; nz *= inv;
    const float third = 1.0f / 3.0f;
    float cx = (s[0] + s[3] + s[6]) * third;
    float cy = (s[1] + s[4] + s[7]) * third;
    float cz = (s[2] + s[5] + s[8]) * third;
    float ux = px - cx, uy = py - cy, uz = pz - cz;
    float h = ux * nx + uy * ny + uz * nz;
    float rx = ux - h * nx, ry = uy - h * ny, rz = uz - h * nz;
    float r = sqrtf(rx * rx + ry * ry + rz * rz);
    float radial = fmaxf(0.0f, 1.0f - 2.0f * r);         // 1 - r/SIGMA
    // relu(-h) + relu(h)*exp(-h/SIGMA) == h<0 ? -h : h*exp(-2h)
    float depth = (h < 0.0f) ? -h : h * expf(-2.0f * h);
    float phi = radial * depth;
    return phi * phi;                                     // POINT2PLANE=False
}

// ---------------------------------------------------------------------------
// Grid-stride wave per receiver. 64 lanes test 64 candidates per chunk;
// ballot bits in lane order = ascending j, so taking the first (8-nc) set
// bits reproduces stable top_k exactly. Penalty spread: lane = k*8 + t,
// t<6 active: d = t>=3 (direction), v = t%3 (vertex). No atomics: each block
// writes a private partial slot.
__global__ __launch_bounds__(256) void coll_kernel(
    const float4* __restrict__ tri,
    const float4* __restrict__ lo4, const float4* __restrict__ hi4,
    const int* __restrict__ f2,
    float* __restrict__ partial)
{
    const int lane = threadIdx.x & 63;
    const int wid  = threadIdx.x >> 6;
    const int gw   = (blockIdx.x * blockDim.x + threadIdx.x) >> 6;
    const int nw   = (gridDim.x * blockDim.x) >> 6;

    float acc = 0.0f;

    for (int i = gw; i < NF; i += nw) {
        float4 rlo = lo4[i], rhi = hi4[i];
        int fa0 = __float_as_int(rlo.w);
        int fa1 = __float_as_int(rhi.w);
        int fa2 = f2[i];

        int nc = 0;
        int hj = -1;                                     // this lane's hit slot
        for (int base = 0; base < NFP && nc < KMAX; base += 64) {
            int j = base + lane;
            float4 jlo = lo4[j];
            float4 jhi = hi4[j];
            int jf2 = f2[j];
            bool ov = (rlo.x <= jhi.x) & (jlo.x <= rhi.x)
                    & (rlo.y <= jhi.y) & (jlo.y <= rhi.y)
                    & (rlo.z <= jhi.z) & (jlo.z <= rhi.z);
            int fb0 = __float_as_int(jlo.w);
            int fb1 = __float_as_int(jhi.w);
            bool share = (fb0 == fa0) | (fb0 == fa1) | (fb0 == fa2)
                       | (fb1 == fa0) | (fb1 == fa1) | (fb1 == fa2)
                       | (jf2 == fa0) | (jf2 == fa1) | (jf2 == fa2);
            bool valid = ov & !share;
            unsigned long long mask = __ballot(valid);
            int cnt  = __popcll(mask);
            int take = min(cnt, KMAX - nc);
            if (lane >= nc && lane < nc + take) {
                int t = lane - nc;                       // t-th set bit
                unsigned long long m = mask;
                for (int q = 0; q < t; ++q) m &= (m - 1);
                hj = base + __builtin_ctzll(m);
            }
            nc += take;
        }

        // Penalty phase
        int k = lane >> 3;                               // pair index 0..7
        int t = lane & 7;                                // term index, t<6 live
        int hjk = __shfl(hj, k);
        float p = 0.0f;
        if (t < 6 && k < nc) {
            int d = (t >= 3) ? 1 : 0;                    // 0: recv field @ intr verts
            int v = t - 3 * d;
            int si = d ? hjk : i;                        // field source tri
            int qi = d ? i : hjk;                        // query tri
            float4 s0 = tri[3 * si + 0];
            float4 s1 = tri[3 * si + 1];
            float4 s2 = tri[3 * si + 2];
            float s[9] = { s0.x, s0.y, s0.z, s0.w, s1.x, s1.y, s1.z, s1.w, s2.x };
            const float* qp = (const float*)(tri + 3 * qi);
            p = cone_pen_v(s, qp[3 * v + 0], qp[3 * v + 1], qp[3 * v + 2]);
        }
        acc += p;
    }

    // 64-lane butterfly, then block reduce, then ONE plain store per block.
#pragma unroll
    for (int off = 32; off > 0; off >>= 1) acc += __shfl_xor(acc, off);
    __shared__ float wsum[4];
    if (lane == 0) wsum[wid] = acc;
    __syncthreads();
    if (threadIdx.x == 0)
        partial[blockIdx.x] = wsum[0] + wsum[1] + wsum[2] + wsum[3];
}

// ---------------------------------------------------------------------------
// Sum the 2048 block partials into the scalar output.
__global__ __launch_bounds__(256) void reduce_kernel(
    const float* __restrict__ partial, float* __restrict__ out)
{
    float a = 0.0f;
    for (int idx = threadIdx.x; idx < CBLK; idx += 256) a += partial[idx];
#pragma unroll
    for (int off = 32; off > 0; off >>= 1) a += __shfl_xor(a, off);
    __shared__ float ws[4];
    int lane = threadIdx.x & 63, wid = threadIdx.x >> 6;
    if (lane == 0) ws[wid] = a;
    __syncthreads();
    if (threadIdx.x == 0) out[0] = ws[0] + ws[1] + ws[2] + ws[3];
}

// ---------------------------------------------------------------------------
extern "C" void kernel_launch(void* const* d_in, const int* in_sizes, int n_in,
                              void* d_out, int out_size, void* d_ws, size_t ws_size,
                              hipStream_t stream) {
    const float* verts = (const float*)d_in[0];   // [1,NV,3] fp32
    const int*   faces = (const int*)d_in[1];     // [NF*3] int32
    float* out = (float*)d_out;                   // scalar fp32

    float4* tri = (float4*)d_ws;                  // NFP*3 float4  (648 KB)
    float4* lo4 = tri + NFP * 3;                  // NFP float4   (216 KB)
    float4* hi4 = lo4 + NFP;                      // NFP float4   (216 KB)
    int*    f2  = (int*)(hi4 + NFP);              // NFP int      ( 54 KB)
    float*  partial = (float*)(f2 + NFP);         // CBLK floats  (  8 KB)

    prep_kernel<<<NFP / 256, 256, 0, stream>>>(verts, faces, tri, lo4, hi4, f2);
    coll_kernel<<<CBLK, 256, 0, stream>>>(tri, lo4, hi4, f2, partial);
    reduce_kernel<<<1, 256, 0, stream>>>(partial, out);
}